// Round 4
// baseline (176.764 us; speedup 1.0000x reference)
//
#include <hip/hip_runtime.h>
#include <math.h>

// Problem constants
#define K_CODES 1024
#define C_DIM   128
#define HW      4096          // 64*64
#define CHW     (C_DIM*HW)    // per-batch stride in x
#define N_POS   65536         // 16*64*64
#define Q_ELEMS 8388608       // 16*128*64*64

// ws layout (byte offsets). Total < 272 KB (proven safe rounds 1-3).
#define WS_S    0             // float: sum of sqrt(d2min)
#define WS_C2   256           // float[1024]: ||c_k||^2
#define WS_IDX  8192          // int[65536]: final argmin index per position

// d_out scratch (overwritten by write_q later; stream-ordered, safe):
//   offset 0: bf16 codebook [k][c], 1024*128*2B = 256 KB

typedef __attribute__((ext_vector_type(8))) short short8;   // 8 bf16 (4 VGPRs)
typedef __attribute__((ext_vector_type(4))) float f32x4;    // MFMA acc

__device__ __forceinline__ unsigned short f2bf(float f) {   // fp32 -> bf16 RNE
    unsigned u = __float_as_uint(f);
    u += 0x7FFFu + ((u >> 16) & 1u);
    return (unsigned short)(u >> 16);
}

// ---------------------------------------------------------------------------
// Kernel 1: prep. Block k: codebook row norm (same math as rounds 1-3) +
// bf16 conversion of the row; block 0 lane 0 zeroes the S accumulator.
// ---------------------------------------------------------------------------
__global__ void prep_kernel(const float* __restrict__ cb, float* __restrict__ ws,
                            unsigned short* __restrict__ cbbf) {
    int k = blockIdx.x;
    int l = threadIdx.x;                       // 64 lanes = 1 wave
    if (k == 0 && l == 0) *(float*)((char*)ws + WS_S) = 0.f;
    float v1 = cb[k * C_DIM + l];
    float v2 = cb[k * C_DIM + 64 + l];
    cbbf[k * C_DIM + l]      = f2bf(v1);
    cbbf[k * C_DIM + 64 + l] = f2bf(v2);
    float ss = v1 * v1 + v2 * v2;
    #pragma unroll
    for (int off = 32; off > 0; off >>= 1) ss += __shfl_down(ss, off);
    if (l == 0) ((float*)((char*)ws + WS_C2))[k] = ss;
}

// ---------------------------------------------------------------------------
// Kernel 2: fused VQ. 1024 blocks x 256 thr; block = 64 positions, wave = 16
// (one 16x16x32 B-tile). 16 chunks of 64 codes, LDS double-buffered A-tiles
// (granule-pad stride 17 -> conflict-spread b128 reads).
// Top-3 tracking: score with 10-bit code idx embedded in low mantissa bits,
// sorted 3-chain via min + 2x v_med3_f32 (6 VALU/score). Then exact fp32
// rescore of the 3 candidates in-kernel (x kept in fp32 VGPRs; cb rows
// gathered float4 from L2) + loss partial + final idx write.
// ---------------------------------------------------------------------------
__global__ __launch_bounds__(256, 4) void vq_mfma(const float* __restrict__ x,
                                                  const float* __restrict__ cb,
                                                  const unsigned short* __restrict__ cbbf,
                                                  const float* __restrict__ c2w,
                                                  int* __restrict__ idxw,
                                                  float* __restrict__ Sw) {
    __shared__ uint4 cbuf[2176];                // 2 x 1088 uint4 = 34816 B

    const int t  = threadIdx.x;
    const int w  = t >> 6;                      // wave 0..3
    const int ln = t & 63;
    const int lp = ln & 15;                     // position lane (n index)
    const int q  = ln >> 4;                     // quad 0..3 (k sub-range)
    const int bid = blockIdx.x;
    const int b   = bid >> 6;                   // batch (64 blocks per image)
    const int sp  = (bid & 63) * 64 + w * 16 + lp;   // spatial position

    // ---- x: fp32 kept in regs (for exact rescore) + bf16 B-frags ----
    // lane holds pos sp, channels c = 32*cs + 8*q + j
    float  xr[4][8];
    short8 xf[4];
    float  ss = 0.f;
    {
        const float* xgp = x + b * CHW + sp;
        #pragma unroll
        for (int cs = 0; cs < 4; ++cs) {
            union { short8 v; unsigned short u[8]; } fu;
            #pragma unroll
            for (int j = 0; j < 8; ++j) {
                float vv = xgp[(32 * cs + 8 * q + j) * HW];
                xr[cs][j] = vv;
                ss = fmaf(vv, vv, ss);
                fu.u[j] = f2bf(vv);
            }
            xf[cs] = fu.v;
        }
        ss += __shfl_xor(ss, 16);
        ss += __shfl_xor(ss, 32);
    }
    const float r2 = -2.0f / fmaxf(sqrtf(ss), 1e-12f);  // F.normalize eps

    // sorted top-3 chain (packed: score with idx in low 10 mantissa bits)
    float m1 = __uint_as_float(0x7F7FFFFFu);
    float m2 = m1, m3 = m1;

    // ---- stage chunk 0 (row stride 17 granules) ----
    {
        const uint4* src4 = (const uint4*)cbbf;
        #pragma unroll
        for (int i = 0; i < 4; ++i) {
            int u = i * 256 + t;
            cbuf[(u >> 4) * 17 + (u & 15)] = src4[u];
        }
    }
    __syncthreads();

    for (int chunk = 0; chunk < 16; ++chunk) {
        const int k0 = chunk << 6;
        const bool more = chunk < 15;

        uint4 pre[4];
        if (more) {
            const uint4* s4 = (const uint4*)cbbf + (k0 + 64) * 16;
            #pragma unroll
            for (int i = 0; i < 4; ++i) pre[i] = s4[i * 256 + t];
        }

        // ---- MFMA: 4 code-tiles x K=128 (4 steps) ----
        f32x4 acc[4];
        #pragma unroll
        for (int ct = 0; ct < 4; ++ct) acc[ct] = 0;
        const unsigned short* cbp = (const unsigned short*)(cbuf + (chunk & 1) * 1088);
        #pragma unroll
        for (int cs = 0; cs < 4; ++cs) {
            short8 ah[4];
            #pragma unroll
            for (int ct = 0; ct < 4; ++ct)   // A[m=lp][k=8q+j], granule 4cs+q
                ah[ct] = *(const short8*)(cbp + ((16 * ct + lp) * 17 + 4 * cs + q) * 8);
            #pragma unroll
            for (int ct = 0; ct < 4; ++ct)
                acc[ct] = __builtin_amdgcn_mfma_f32_16x16x32_bf16(
                    ah[ct], xf[cs], acc[ct], 0, 0, 0);
        }

        if (more) {
            uint4* dst = cbuf + ((chunk & 1) ^ 1) * 1088;
            #pragma unroll
            for (int i = 0; i < 4; ++i) {
                int u = i * 256 + t;
                dst[(u >> 4) * 17 + (u & 15)] = pre[i];
            }
        }

        // ---- epilogue: 16 scores, 6 VALU each ----
        #pragma unroll
        for (int ct = 0; ct < 4; ++ct) {
            float4 c2v = *(const float4*)(c2w + k0 + 16 * ct + 4 * q);
            float c2a[4] = {c2v.x, c2v.y, c2v.z, c2v.w};
            const int kb0 = k0 + 16 * ct + 4 * q;
            #pragma unroll
            for (int reg = 0; reg < 4; ++reg) {
                float s = fmaf(r2, acc[ct][reg], c2a[reg]);
                unsigned pb = (__float_as_uint(s) & 0xFFFFFC00u) |
                              (unsigned)(kb0 + reg);
                float u  = __uint_as_float(pb);
                float t3 = __builtin_amdgcn_fmed3f(m2, m3, u);
                float t2 = __builtin_amdgcn_fmed3f(m1, m2, u);
                m1 = fminf(m1, u); m2 = t2; m3 = t3;
            }
        }
        __syncthreads();
    }

    // ---- merge top-3 across the 4 quad-lanes of each position ----
    #pragma unroll
    for (int d = 16; d <= 32; d <<= 1) {
        float o1 = __shfl_xor(m1, d), o2 = __shfl_xor(m2, d), o3 = __shfl_xor(m3, d);
        float u, t2, t3;
        u = o1; t3 = __builtin_amdgcn_fmed3f(m2, m3, u);
        t2 = __builtin_amdgcn_fmed3f(m1, m2, u); m1 = fminf(m1, u); m2 = t2; m3 = t3;
        u = o2; t3 = __builtin_amdgcn_fmed3f(m2, m3, u);
        t2 = __builtin_amdgcn_fmed3f(m1, m2, u); m1 = fminf(m1, u); m2 = t2; m3 = t3;
        u = o3; t3 = __builtin_amdgcn_fmed3f(m2, m3, u);
        t2 = __builtin_amdgcn_fmed3f(m1, m2, u); m1 = fminf(m1, u); m2 = t2; m3 = t3;
    }
    int ks[3] = {(int)(__float_as_uint(m1) & 1023u),
                 (int)(__float_as_uint(m2) & 1023u),
                 (int)(__float_as_uint(m3) & 1023u)};

    // ---- exact fp32 rescore of the 3 candidates ----
    float dots[3];
    #pragma unroll
    for (int j = 0; j < 3; ++j) {
        const float* crow = cb + ks[j] * C_DIM + 8 * q;
        float p = 0.f;
        #pragma unroll
        for (int cs = 0; cs < 4; ++cs) {
            float4 a0 = *(const float4*)(crow + 32 * cs);
            float4 a1 = *(const float4*)(crow + 32 * cs + 4);
            p = fmaf(xr[cs][0], a0.x, p); p = fmaf(xr[cs][1], a0.y, p);
            p = fmaf(xr[cs][2], a0.z, p); p = fmaf(xr[cs][3], a0.w, p);
            p = fmaf(xr[cs][4], a1.x, p); p = fmaf(xr[cs][5], a1.y, p);
            p = fmaf(xr[cs][6], a1.z, p); p = fmaf(xr[cs][7], a1.w, p);
        }
        p += __shfl_xor(p, 16);
        p += __shfl_xor(p, 32);
        dots[j] = p;
    }
    float sb = fmaf(r2, dots[0], c2w[ks[0]]); int kb = ks[0];
    float s2 = fmaf(r2, dots[1], c2w[ks[1]]);
    if (s2 < sb || (s2 == sb && ks[1] < kb)) { sb = s2; kb = ks[1]; }
    float s3 = fmaf(r2, dots[2], c2w[ks[2]]);
    if (s3 < sb || (s3 == sb && ks[2] < kb)) { sb = s3; kb = ks[2]; }

    if (ln < 16) idxw[bid * 64 + w * 16 + lp] = kb;

    // loss: every q-lane holds identical sb -> full-wave reduce, scale 0.25
    float l = sqrtf(fmaxf(1.0f + sb, 0.f));
    #pragma unroll
    for (int off = 32; off > 0; off >>= 1) l += __shfl_down(l, off);
    if (ln == 0) atomicAdd(Sw, 0.25f * l);
}

// ---------------------------------------------------------------------------
// Kernel 3: scatter q = codebook[idx] back to [B,C,H,W] (overwrites scratch)
// ---------------------------------------------------------------------------
__global__ void write_q(const float* __restrict__ cb,
                        const float* __restrict__ ws,
                        float* __restrict__ out) {
    const int* idxw = (const int*)((const char*)ws + WS_IDX);
    int e = blockIdx.x * 256 + threadIdx.x;   // float4 id, 2097152 total
    int f = e << 2;
    int s = f & 4095;
    int c = (f >> 12) & 127;
    int b = f >> 19;
    int4 iv = *(const int4*)(idxw + b * HW + s);
    float4 o;
    o.x = cb[iv.x * C_DIM + c];
    o.y = cb[iv.y * C_DIM + c];
    o.z = cb[iv.z * C_DIM + c];
    o.w = cb[iv.w * C_DIM + c];
    ((float4*)out)[e] = o;
}

// ---------------------------------------------------------------------------
// Kernel 4: finalize losses. loss = mean over N of sqrt(d2min); lw=(0.25, 1.0)
// ---------------------------------------------------------------------------
__global__ void fin_kernel(const float* __restrict__ ws, float* __restrict__ out) {
    float S = *(const float*)((const char*)ws + WS_S);
    float m = S / (float)N_POS;
    out[Q_ELEMS]     = 0.25f * m;
    out[Q_ELEMS + 1] = m;
}

extern "C" void kernel_launch(void* const* d_in, const int* in_sizes, int n_in,
                              void* d_out, int out_size, void* d_ws, size_t ws_size,
                              hipStream_t stream) {
    const float* x  = (const float*)d_in[0];   // [16,128,64,64]
    const float* cb = (const float*)d_in[1];   // [1024,128]
    float* out = (float*)d_out;
    float* ws  = (float*)d_ws;

    const float* c2w = (const float*)((const char*)d_ws + WS_C2);
    int*  idxw = (int*)((char*)d_ws + WS_IDX);
    float* Sw  = (float*)((char*)d_ws + WS_S);
    unsigned short* cbbf = (unsigned short*)d_out;   // scratch in d_out

    prep_kernel<<<K_CODES, 64, 0, stream>>>(cb, ws, cbbf);
    vq_mfma    <<<N_POS / 64, 256, 0, stream>>>(x, cb, cbbf, c2w, idxw, Sw);
    write_q    <<<Q_ELEMS / 1024, 256, 0, stream>>>(cb, ws, out);
    fin_kernel <<<1, 1, 0, stream>>>(ws, out);
}